// Round 1
// baseline (529.315 us; speedup 1.0000x reference)
//
#include <hip/hip_runtime.h>

#define N_ROWS 16384
#define D 128
#define QBLK 128
#define KVTILE 64
#define NSPLIT 4
#define KV_PER_SPLIT (N_ROWS / NSPLIT)
#define TILES_PER_SPLIT (KV_PER_SPLIT / KVTILE)
#define TAU 1.0f
#define SCALE 1.0f
#define LN_EPS 1e-5f
#define L2_EPS 1e-12f

typedef float f32x4 __attribute__((ext_vector_type(4)));
typedef short s16x8 __attribute__((ext_vector_type(8)));
typedef unsigned short u16;

__device__ __forceinline__ u16 f2bf(float f) {
    union { float f; unsigned u; } v; v.f = f;
    unsigned r = v.u + 0x7FFFu + ((v.u >> 16) & 1u);   // RNE
    return (u16)(r >> 16);
}
__device__ __forceinline__ float bf2f(u16 h) {
    union { unsigned u; float f; } v; v.u = ((unsigned)h) << 16; return v.f;
}

// ---------------- prep: invnrm[i] = 1 / max(||x_i||, eps) ----------------
__global__ __launch_bounds__(256) void prep_norms(const float* __restrict__ x,
                                                  float* __restrict__ invnrm) {
    int t = threadIdx.x;
    int row = blockIdx.x * 64 + (t >> 2);
    int q = t & 3;
    const float4* xr = (const float4*)(x + (size_t)row * D);
    float s = 0.f;
#pragma unroll
    for (int i = 0; i < 8; ++i) {
        float4 v = xr[q * 8 + i];
        s += v.x * v.x + v.y * v.y + v.z * v.z + v.w * v.w;
    }
    s += __shfl_xor(s, 1);
    s += __shfl_xor(s, 2);
    if (q == 0) invnrm[row] = 1.0f / fmaxf(sqrtf(s), L2_EPS);
}

// ---------------- fused flash attention (no online max needed: |s|<=~1) ----
// K LDS: [64 kv][128 d] bf16, row stride 256B, swizzle byte ^= (kv&7)<<4
// V LDS: [128 d][64 kv] bf16 (transposed), stride 128B, swizzle ^= (d&7)<<4
// P LDS: [128 qr][64 kv] bf16, stride 128B, swizzle ^= (qr&7)<<4
__device__ __forceinline__ void stage_kv(const float* __restrict__ x,
                                         const float* __restrict__ invnrm,
                                         int kvbase, u16* sK, u16* sV, int tid) {
#pragma unroll
    for (int it = 0; it < 8; ++it) {
        int item = it * 256 + tid;   // 0..2047 = 128 cols x 16 kv-quads
        int c = item & 127;
        int q4 = item >> 7;
        int kv = 4 * q4;
        const float* col = x + (size_t)(kvbase + kv) * D + c;
        float v0 = col[0], v1 = col[D], v2 = col[2 * D], v3 = col[3 * D];
        float i0 = invnrm[kvbase + kv + 0];
        float i1 = invnrm[kvbase + kv + 1];
        float i2 = invnrm[kvbase + kv + 2];
        float i3 = invnrm[kvbase + kv + 3];
        *(u16*)((char*)sK + (kv + 0) * 256 + ((2 * c) ^ (((kv + 0) & 7) << 4))) = f2bf(v0 * i0);
        *(u16*)((char*)sK + (kv + 1) * 256 + ((2 * c) ^ (((kv + 1) & 7) << 4))) = f2bf(v1 * i1);
        *(u16*)((char*)sK + (kv + 2) * 256 + ((2 * c) ^ (((kv + 2) & 7) << 4))) = f2bf(v2 * i2);
        *(u16*)((char*)sK + (kv + 3) * 256 + ((2 * c) ^ (((kv + 3) & 7) << 4))) = f2bf(v3 * i3);
        ushort4 pk;
        pk.x = f2bf(v0); pk.y = f2bf(v1); pk.z = f2bf(v2); pk.w = f2bf(v3);
        *(ushort4*)((char*)sV + c * 128 + ((2 * kv) ^ ((c & 7) << 4))) = pk;
    }
}

__global__ __launch_bounds__(256) void attn(const float* __restrict__ x,
                                            const float* __restrict__ invnrm,
                                            float* __restrict__ num,
                                            float* __restrict__ denom) {
    __shared__ __align__(16) u16 sK[KVTILE * D];     // 16 KB
    __shared__ __align__(16) u16 sV[D * KVTILE];     // 16 KB
    __shared__ __align__(16) u16 sP[QBLK * KVTILE];  // 16 KB

    const int bx = blockIdx.x;
    const int qb = bx >> 2;          // 0..127
    const int sp = bx & 3;           // 0..3
    const int qrow0 = qb * QBLK;
    const int kv0 = sp * KV_PER_SPLIT;

    const int tid = threadIdx.x;
    const int w = tid >> 6;
    const int lane = tid & 63;
    const int g = lane >> 4;
    const int ln = lane & 15;

    // --- load Q fragments straight from global (once per block), scaled ---
    s16x8 qf[2][4];
#pragma unroll
    for (int rt = 0; rt < 2; ++rt) {
#pragma unroll
        for (int ks = 0; ks < 4; ++ks) {
            int row = qrow0 + 32 * w + 16 * rt + ln;
            float inv = invnrm[row];
            const float* p = x + (size_t)row * D + 32 * ks + 8 * g;
            float4 a = *(const float4*)p;
            float4 b = *(const float4*)(p + 4);
            s16x8 qv;
            qv[0] = (short)f2bf(a.x * inv); qv[1] = (short)f2bf(a.y * inv);
            qv[2] = (short)f2bf(a.z * inv); qv[3] = (short)f2bf(a.w * inv);
            qv[4] = (short)f2bf(b.x * inv); qv[5] = (short)f2bf(b.y * inv);
            qv[6] = (short)f2bf(b.z * inv); qv[7] = (short)f2bf(b.w * inv);
            qf[rt][ks] = qv;
        }
    }

    f32x4 acc[2][8];
#pragma unroll
    for (int rt = 0; rt < 2; ++rt)
#pragma unroll
        for (int dt = 0; dt < 8; ++dt) acc[rt][dt] = (f32x4){0.f, 0.f, 0.f, 0.f};
    float rowsum[2][4] = {{0.f, 0.f, 0.f, 0.f}, {0.f, 0.f, 0.f, 0.f}};

    for (int tile = 0; tile < TILES_PER_SPLIT; ++tile) {
        __syncthreads();                       // prev PV reads done
        stage_kv(x, invnrm, kv0 + tile * KVTILE, sK, sV, tid);
        __syncthreads();                       // K/V staged

        // ---- S = Qn Kn^T, P = exp(S/tau) -> sP + rowsum ----
#pragma unroll
        for (int ct = 0; ct < 4; ++ct) {
            s16x8 kf[4];
#pragma unroll
            for (int ks = 0; ks < 4; ++ks) {
                int kvr = 16 * ct + ln;
                kf[ks] = *(const s16x8*)((const char*)sK + kvr * 256 +
                                         ((64 * ks + 16 * g) ^ ((kvr & 7) << 4)));
            }
#pragma unroll
            for (int rt = 0; rt < 2; ++rt) {
                f32x4 s = (f32x4){0.f, 0.f, 0.f, 0.f};
#pragma unroll
                for (int ks = 0; ks < 4; ++ks)
                    s = __builtin_amdgcn_mfma_f32_16x16x32_bf16(qf[rt][ks], kf[ks], s, 0, 0, 0);
#pragma unroll
                for (int r = 0; r < 4; ++r) {
                    float p = __expf(s[r] * (1.0f / TAU));
                    u16 pb = f2bf(p);
                    rowsum[rt][r] += bf2f(pb);   // denom consistent with numerator
                    int prow = 32 * w + 16 * rt + 4 * g + r;
                    int pcol = 16 * ct + ln;
                    *(u16*)((char*)sP + prow * 128 + ((2 * pcol) ^ ((prow & 7) << 4))) = pb;
                }
            }
        }
        __syncthreads();                       // sP visible

        // ---- O += P V ----
#pragma unroll
        for (int ks2 = 0; ks2 < 2; ++ks2) {
            s16x8 af[2];
#pragma unroll
            for (int rt = 0; rt < 2; ++rt) {
                int arow = 32 * w + 16 * rt + ln;
                af[rt] = *(const s16x8*)((const char*)sP + arow * 128 +
                                         ((64 * ks2 + 16 * g) ^ ((arow & 7) << 4)));
            }
#pragma unroll
            for (int dt = 0; dt < 8; ++dt) {
                int d = 16 * dt + ln;
                s16x8 vf = *(const s16x8*)((const char*)sV + d * 128 +
                                           ((64 * ks2 + 16 * g) ^ ((d & 7) << 4)));
#pragma unroll
                for (int rt = 0; rt < 2; ++rt)
                    acc[rt][dt] = __builtin_amdgcn_mfma_f32_16x16x32_bf16(af[rt], vf, acc[rt][dt], 0, 0, 0);
            }
        }
    }

    // ---- epilogue: combine partials via device-scope atomics ----
#pragma unroll
    for (int rt = 0; rt < 2; ++rt) {
#pragma unroll
        for (int r = 0; r < 4; ++r) {
            float s = rowsum[rt][r];
            s += __shfl_xor(s, 1);
            s += __shfl_xor(s, 2);
            s += __shfl_xor(s, 4);
            s += __shfl_xor(s, 8);
            if (ln == 0)
                atomicAdd(&denom[qrow0 + 32 * w + 16 * rt + 4 * g + r], s);
        }
    }
#pragma unroll
    for (int rt = 0; rt < 2; ++rt)
#pragma unroll
        for (int dt = 0; dt < 8; ++dt)
#pragma unroll
            for (int r = 0; r < 4; ++r) {
                int row = qrow0 + 32 * w + 16 * rt + 4 * g + r;
                int col = 16 * dt + ln;
                atomicAdd(&num[(size_t)row * D + col], acc[rt][dt][r]);
            }
}

// ---------------- finalize: y = 2x - num/denom ; LayerNorm ----------------
__global__ __launch_bounds__(256) void finalize(const float* __restrict__ x,
                                                const float* __restrict__ gamma,
                                                const float* __restrict__ beta,
                                                const float* __restrict__ denom,
                                                float* __restrict__ out) {  // out == num, in place
    int t = threadIdx.x;
    int row = blockIdx.x * 64 + (t >> 2);
    int q = t & 3;
    float invd = 1.0f / denom[row];
    const float4* xr = (const float4*)(x + (size_t)row * D);
    const float4* nr = (const float4*)(out + (size_t)row * D);
    float y[32];
    float s1 = 0.f, s2 = 0.f;
#pragma unroll
    for (int i = 0; i < 8; ++i) {
        float4 xv = xr[q * 8 + i];
        float4 nv = nr[q * 8 + i];
#pragma unroll
        for (int j = 0; j < 4; ++j) {
            float yv = (1.0f + SCALE) * (&xv.x)[j] - SCALE * ((&nv.x)[j] * invd);
            y[i * 4 + j] = yv;
            s1 += yv;
            s2 += yv * yv;
        }
    }
    s1 += __shfl_xor(s1, 1); s1 += __shfl_xor(s1, 2);
    s2 += __shfl_xor(s2, 1); s2 += __shfl_xor(s2, 2);
    float mu = s1 * (1.0f / D);
    float var = s2 * (1.0f / D) - mu * mu;
    float rstd = rsqrtf(var + LN_EPS);
    float4* orow = (float4*)(out + (size_t)row * D);
#pragma unroll
    for (int i = 0; i < 8; ++i) {
        int c = q * 32 + i * 4;
        float4 o;
#pragma unroll
        for (int j = 0; j < 4; ++j)
            (&o.x)[j] = (y[i * 4 + j] - mu) * rstd * gamma[c + j] + beta[c + j];
        orow[q * 8 + i] = o;
    }
}

extern "C" void kernel_launch(void* const* d_in, const int* in_sizes, int n_in,
                              void* d_out, int out_size, void* d_ws, size_t ws_size,
                              hipStream_t stream) {
    const float* x = (const float*)d_in[0];
    const float* gamma = (const float*)d_in[1];
    const float* beta = (const float*)d_in[2];
    float* out = (float*)d_out;
    float* invnrm = (float*)d_ws;             // N floats
    float* denom = invnrm + N_ROWS;           // N floats  (ws use: 128 KB)

    hipMemsetAsync(d_out, 0, (size_t)N_ROWS * D * sizeof(float), stream);  // num accumulator
    hipMemsetAsync(denom, 0, (size_t)N_ROWS * sizeof(float), stream);

    prep_norms<<<N_ROWS / 64, 256, 0, stream>>>(x, invnrm);
    attn<<<(N_ROWS / QBLK) * NSPLIT, 256, 0, stream>>>(x, invnrm, out, denom);
    finalize<<<N_ROWS / 64, 256, 0, stream>>>(x, gamma, beta, denom, out);
}

// Round 2
// 349.382 us; speedup vs baseline: 1.5150x; 1.5150x over previous
//
#include <hip/hip_runtime.h>
#include <hip/hip_bf16.h>

#define N_ROWS 16384
#define D 128
#define QBLK 128
#define KVTILE 64
#define NSPLIT 8
#define KV_PER_SPLIT (N_ROWS / NSPLIT)
#define TILES_PER_SPLIT (KV_PER_SPLIT / KVTILE)
#define TAU 1.0f
#define SCALE 1.0f
#define LN_EPS 1e-5f
#define L2_EPS 1e-12f

typedef float f32x16 __attribute__((ext_vector_type(16)));
typedef short s16x8 __attribute__((ext_vector_type(8)));
typedef unsigned short u16;

__device__ __forceinline__ u16 f2bf(float f) {
    union { float f; unsigned u; } v; v.f = f;
    unsigned r = v.u + 0x7FFFu + ((v.u >> 16) & 1u);   // RNE
    return (u16)(r >> 16);
}
__device__ __forceinline__ unsigned pk2(float lo, float hi) {
    // compiler emits v_cvt_pk_bf16_f32 from paired casts (m240)
    union { __hip_bfloat162 b; unsigned u; } c;
    c.b = __float22bfloat162_rn(float2{lo, hi});
    return c.u;
}

// ---------------- prep: invnrm[i] = 1 / max(||x_i||, eps) ----------------
__global__ __launch_bounds__(256) void prep_norms(const float* __restrict__ x,
                                                  float* __restrict__ invnrm) {
    int t = threadIdx.x;
    int row = blockIdx.x * 64 + (t >> 2);
    int q = t & 3;
    const float4* xr = (const float4*)(x + (size_t)row * D);
    float s = 0.f;
#pragma unroll
    for (int i = 0; i < 8; ++i) {
        float4 v = xr[q * 8 + i];
        s += v.x * v.x + v.y * v.y + v.z * v.z + v.w * v.w;
    }
    s += __shfl_xor(s, 1);
    s += __shfl_xor(s, 2);
    if (q == 0) invnrm[row] = 1.0f / fmaxf(sqrtf(s), L2_EPS);
}

// K LDS: [64 kv][128 d] bf16, row 256B, 16B-chunk swizzle c16 ^= (kv&7)
// V LDS: [128 d][64 kv] bf16 (transposed), row 128B, chunk swizzle ^= (d&7)
__device__ __forceinline__ void stage_kv(const float* __restrict__ x,
                                         const float* __restrict__ invnrm,
                                         int kvbase, u16* sK, u16* sV, int tid) {
    // ---- K: row-chunk loads -> packed b128 writes ----
#pragma unroll
    for (int it = 0; it < 4; ++it) {
        int chunk = it * 256 + tid;        // 0..1023
        int row = chunk >> 4;              // 0..63
        int c16 = chunk & 15;              // 16B chunk within row
        const float* p = x + (size_t)(kvbase + row) * D + 8 * c16;
        float inv = invnrm[kvbase + row];
        float4 a = *(const float4*)p;
        float4 b = *(const float4*)(p + 4);
        union { u16 s[8]; s16x8 v; } pk;
        pk.s[0] = f2bf(a.x * inv); pk.s[1] = f2bf(a.y * inv);
        pk.s[2] = f2bf(a.z * inv); pk.s[3] = f2bf(a.w * inv);
        pk.s[4] = f2bf(b.x * inv); pk.s[5] = f2bf(b.y * inv);
        pk.s[6] = f2bf(b.z * inv); pk.s[7] = f2bf(b.w * inv);
        *(s16x8*)((char*)sK + row * 256 + 16 * (c16 ^ (row & 7))) = pk.v;
    }
    // ---- V^T: column loads -> b64 writes ----
#pragma unroll
    for (int it = 0; it < 8; ++it) {
        int item = it * 256 + tid;
        int c = item & 127;                // d column
        int q4 = item >> 7;                // 0..15, kv quad
        int kv = 4 * q4;
        const float* col = x + (size_t)(kvbase + kv) * D + c;
        ushort4 w;
        w.x = f2bf(col[0]);     w.y = f2bf(col[D]);
        w.z = f2bf(col[2 * D]); w.w = f2bf(col[3 * D]);
        int byteoff = 16 * ((q4 >> 1) ^ (c & 7)) + 8 * (q4 & 1);
        *(ushort4*)((char*)sV + c * 128 + byteoff) = w;
    }
}

__global__ __launch_bounds__(256, 3) void attn(const float* __restrict__ x,
                                               const float* __restrict__ invnrm,
                                               float* __restrict__ num,
                                               float* __restrict__ denom) {
    __shared__ __align__(16) u16 sK[KVTILE * D];     // 16 KB
    __shared__ __align__(16) u16 sV[D * KVTILE];     // 16 KB

    const int bx = blockIdx.x;
    const int qb = bx >> 3;          // 0..127
    const int sp = bx & 7;           // 0..7  (== XCD under %8 round-robin)
    const int qrow0 = qb * QBLK;
    const int kv0 = sp * KV_PER_SPLIT;

    const int tid = threadIdx.x;
    const int w = tid >> 6;
    const int lane = tid & 63;
    const int h = lane >> 5;         // half-wave
    const int ln5 = lane & 31;

    // --- Q B-fragments in registers (col=ln5=q, k=d=8h+j per 16-d step) ---
    const int q = qrow0 + 32 * w + ln5;
    const float invq = invnrm[q];
    s16x8 qf[8];
#pragma unroll
    for (int ks = 0; ks < 8; ++ks) {
        const float* p = x + (size_t)q * D + 16 * ks + 8 * h;
        float4 a = *(const float4*)p;
        float4 b = *(const float4*)(p + 4);
        union { u16 s[8]; s16x8 v; } pk;
        pk.s[0] = f2bf(a.x * invq); pk.s[1] = f2bf(a.y * invq);
        pk.s[2] = f2bf(a.z * invq); pk.s[3] = f2bf(a.w * invq);
        pk.s[4] = f2bf(b.x * invq); pk.s[5] = f2bf(b.y * invq);
        pk.s[6] = f2bf(b.z * invq); pk.s[7] = f2bf(b.w * invq);
        qf[ks] = pk.v;
    }

    f32x16 acc[4];
#pragma unroll
    for (int dt = 0; dt < 4; ++dt)
#pragma unroll
        for (int r = 0; r < 16; ++r) acc[dt][r] = 0.f;
    float rowsum = 0.f;

    for (int tile = 0; tile < TILES_PER_SPLIT; ++tile) {
        __syncthreads();                       // prev compute done
        stage_kv(x, invnrm, kv0 + tile * KVTILE, sK, sV, tid);
        __syncthreads();                       // K/V staged

#pragma unroll
        for (int ct = 0; ct < 2; ++ct) {
            // ---- S^T[kv=32ct+.., q] = K Q^T over d=128 ----
            f32x16 s;
#pragma unroll
            for (int r = 0; r < 16; ++r) s[r] = 0.f;
            const int kvr = 32 * ct + ln5;
            const char* krow = (const char*)sK + kvr * 256;
#pragma unroll
            for (int ks = 0; ks < 8; ++ks) {
                s16x8 kf = *(const s16x8*)(krow + 16 * ((2 * ks + h) ^ (ln5 & 7)));
                s = __builtin_amdgcn_mfma_f32_32x32x16_bf16(kf, qf[ks], s, 0, 0, 0);
            }
            // ---- P = exp(S/tau), row q = ln5 entirely in registers ----
            float p[16];
#pragma unroll
            for (int r = 0; r < 16; ++r) {
                p[r] = __expf(s[r] * (1.0f / TAU));
                rowsum += p[r];
            }
            // pack to bf16 dwords and exchange halves (lane ^ 32)
            unsigned d0[4], d1[4], s0[4], s1[4];
#pragma unroll
            for (int m = 0; m < 4; ++m) {
                d0[m] = pk2(p[4 * m + 0], p[4 * m + 1]);
                d1[m] = pk2(p[4 * m + 2], p[4 * m + 3]);
            }
#pragma unroll
            for (int m = 0; m < 4; ++m) {
                s0[m] = (unsigned)__shfl_xor((int)d0[m], 32);
                s1[m] = (unsigned)__shfl_xor((int)d1[m], 32);
            }
            // ---- O += P V  (A=P from regs, B=V^T from LDS) ----
#pragma unroll
            for (int kt2 = 0; kt2 < 2; ++kt2) {
                union { unsigned u[4]; s16x8 v; } A;
                A.u[0] = h ? s0[2 * kt2 + 1] : d0[2 * kt2];
                A.u[1] = h ? s1[2 * kt2 + 1] : d1[2 * kt2];
                A.u[2] = h ? d0[2 * kt2 + 1] : s0[2 * kt2];
                A.u[3] = h ? d1[2 * kt2 + 1] : s1[2 * kt2];
                const int ktg = 2 * ct + kt2;
#pragma unroll
                for (int dt = 0; dt < 4; ++dt) {
                    int dd = 32 * dt + ln5;
                    s16x8 vf = *(const s16x8*)((const char*)sV + dd * 128 +
                                               16 * ((2 * ktg + h) ^ (ln5 & 7)));
                    acc[dt] = __builtin_amdgcn_mfma_f32_32x32x16_bf16(A.v, vf, acc[dt], 0, 0, 0);
                }
            }
        }
    }

    // ---- epilogue ----
    float tot = rowsum + __shfl_xor(rowsum, 32);
    if (h == 0) atomicAdd(&denom[q], tot);
#pragma unroll
    for (int dt = 0; dt < 4; ++dt)
#pragma unroll
        for (int r = 0; r < 16; ++r) {
            int qr = qrow0 + 32 * w + (r & 3) + 8 * (r >> 2) + 4 * h;
            atomicAdd(&num[(size_t)qr * D + 32 * dt + ln5], acc[dt][r]);
        }
}

// ---------------- finalize: y = 2x - num/denom ; LayerNorm ----------------
__global__ __launch_bounds__(256) void finalize(const float* __restrict__ x,
                                                const float* __restrict__ gamma,
                                                const float* __restrict__ beta,
                                                const float* __restrict__ denom,
                                                float* __restrict__ out) {  // out == num, in place
    int t = threadIdx.x;
    int row = blockIdx.x * 64 + (t >> 2);
    int q = t & 3;
    float invd = 1.0f / denom[row];
    const float4* xr = (const float4*)(x + (size_t)row * D);
    const float4* nr = (const float4*)(out + (size_t)row * D);
    float y[32];
    float s1 = 0.f, s2 = 0.f;
#pragma unroll
    for (int i = 0; i < 8; ++i) {
        float4 xv = xr[q * 8 + i];
        float4 nv = nr[q * 8 + i];
#pragma unroll
        for (int j = 0; j < 4; ++j) {
            float yv = (1.0f + SCALE) * (&xv.x)[j] - SCALE * ((&nv.x)[j] * invd);
            y[i * 4 + j] = yv;
            s1 += yv;
            s2 += yv * yv;
        }
    }
    s1 += __shfl_xor(s1, 1); s1 += __shfl_xor(s1, 2);
    s2 += __shfl_xor(s2, 1); s2 += __shfl_xor(s2, 2);
    float mu = s1 * (1.0f / D);
    float var = s2 * (1.0f / D) - mu * mu;
    float rstd = rsqrtf(var + LN_EPS);
    float4* orow = (float4*)(out + (size_t)row * D);
#pragma unroll
    for (int i = 0; i < 8; ++i) {
        int c = q * 32 + i * 4;
        float4 o;
#pragma unroll
        for (int j = 0; j < 4; ++j)
            (&o.x)[j] = (y[i * 4 + j] - mu) * rstd * gamma[c + j] + beta[c + j];
        orow[q * 8 + i] = o;
    }
}

extern "C" void kernel_launch(void* const* d_in, const int* in_sizes, int n_in,
                              void* d_out, int out_size, void* d_ws, size_t ws_size,
                              hipStream_t stream) {
    const float* x = (const float*)d_in[0];
    const float* gamma = (const float*)d_in[1];
    const float* beta = (const float*)d_in[2];
    float* out = (float*)d_out;
    float* invnrm = (float*)d_ws;             // N floats
    float* denom = invnrm + N_ROWS;           // N floats

    hipMemsetAsync(d_out, 0, (size_t)N_ROWS * D * sizeof(float), stream);  // num accumulator
    hipMemsetAsync(denom, 0, (size_t)N_ROWS * sizeof(float), stream);

    prep_norms<<<N_ROWS / 64, 256, 0, stream>>>(x, invnrm);
    attn<<<(N_ROWS / QBLK) * NSPLIT, 256, 0, stream>>>(x, invnrm, out, denom);
    finalize<<<N_ROWS / 64, 256, 0, stream>>>(x, gamma, beta, denom, out);
}

// Round 3
// 248.561 us; speedup vs baseline: 2.1295x; 1.4056x over previous
//
#include <hip/hip_runtime.h>
#include <hip/hip_bf16.h>

#define N_ROWS 16384
#define D 128
#define QBLK 128
#define KVTILE 64
#define NSPLIT 8
#define KV_PER_SPLIT (N_ROWS / NSPLIT)
#define NT (KV_PER_SPLIT / KVTILE)
#define TAU 1.0f
#define SCALE 1.0f
#define LN_EPS 1e-5f
#define L2_EPS 1e-12f

typedef float f32x16 __attribute__((ext_vector_type(16)));
typedef short s16x8 __attribute__((ext_vector_type(8)));
typedef unsigned short u16;

__device__ __forceinline__ unsigned pk2(float lo, float hi) {
    union { __hip_bfloat162 b; unsigned u; } c;
    c.b = __float22bfloat162_rn(float2{lo, hi});
    return c.u;
}
__device__ __forceinline__ float elemf(float4 v, int c) {
    return c == 0 ? v.x : c == 1 ? v.y : c == 2 ? v.z : v.w;
}

// ---------------- prep: invnrm[i] = 1 / max(||x_i||, eps) ----------------
__global__ __launch_bounds__(256) void prep_norms(const float* __restrict__ x,
                                                  float* __restrict__ invnrm) {
    int t = threadIdx.x;
    int row = blockIdx.x * 64 + (t >> 2);
    int q = t & 3;
    const float4* xr = (const float4*)(x + (size_t)row * D);
    float s = 0.f;
#pragma unroll
    for (int i = 0; i < 8; ++i) {
        float4 v = xr[q * 8 + i];
        s += v.x * v.x + v.y * v.y + v.z * v.z + v.w * v.w;
    }
    s += __shfl_xor(s, 1);
    s += __shfl_xor(s, 2);
    if (q == 0) invnrm[row] = 1.0f / fmaxf(sqrtf(s), L2_EPS);
}

// LDS layouts (per buffer, 16 KB each):
//  sK: [64 kv][16 chunks of 16B] bf16 rows of d; chunk stored at c16 ^ (kv & 15)
//  sV: [64 r][16 chunks]; r = d>>1; logical chunk cc = 8*(d&1) + (kv>>3),
//      stored at (cc + r) & 15 (rotation). Element byte within chunk = 2*(kv&7).
__device__ __forceinline__ void stage_load(const float* __restrict__ x,
                                           const float* __restrict__ invnrm,
                                           int kvb, int tid,
                                           float4 (&kr)[4][2], float (&kinv)[4],
                                           float4 (&vr)[8]) {
#pragma unroll
    for (int it = 0; it < 4; ++it) {
        int chunk = it * 256 + tid;
        int row = chunk >> 4, c16 = chunk & 15;
        const float4* p = (const float4*)(x + (size_t)(kvb + row) * D + 8 * c16);
        kr[it][0] = p[0];
        kr[it][1] = p[1];
        kinv[it] = invnrm[kvb + row];
    }
    int dq = tid & 31, q8 = tid >> 5;
#pragma unroll
    for (int j = 0; j < 8; ++j)
        vr[j] = *(const float4*)(x + (size_t)(kvb + 8 * q8 + j) * D + 4 * dq);
}

__device__ __forceinline__ void stage_write(int tid, u16* nK, u16* nV,
                                            const float4 (&kr)[4][2],
                                            const float (&kinv)[4],
                                            const float4 (&vr)[8]) {
#pragma unroll
    for (int it = 0; it < 4; ++it) {
        int chunk = it * 256 + tid;
        int row = chunk >> 4, c16 = chunk & 15;
        float inv = kinv[it];
        union { unsigned u[4]; s16x8 v; } pk;
        pk.u[0] = pk2(kr[it][0].x * inv, kr[it][0].y * inv);
        pk.u[1] = pk2(kr[it][0].z * inv, kr[it][0].w * inv);
        pk.u[2] = pk2(kr[it][1].x * inv, kr[it][1].y * inv);
        pk.u[3] = pk2(kr[it][1].z * inv, kr[it][1].w * inv);
        *(s16x8*)((char*)nK + row * 256 + 16 * (c16 ^ (row & 15))) = pk.v;
    }
    int dq = tid & 31, q8 = tid >> 5;
#pragma unroll
    for (int c = 0; c < 4; ++c) {
        int d = 4 * dq + c;
        int r = d >> 1;
        int ccp = ((8 * (c & 1) + q8) + r) & 15;
        union { unsigned u[4]; s16x8 v; } pk;
        pk.u[0] = pk2(elemf(vr[0], c), elemf(vr[1], c));
        pk.u[1] = pk2(elemf(vr[2], c), elemf(vr[3], c));
        pk.u[2] = pk2(elemf(vr[4], c), elemf(vr[5], c));
        pk.u[3] = pk2(elemf(vr[6], c), elemf(vr[7], c));
        *(s16x8*)((char*)nV + r * 256 + 16 * ccp) = pk.v;
    }
}

__global__ __launch_bounds__(256, 2) void attn(const float* __restrict__ x,
                                               const float* __restrict__ invnrm,
                                               float* __restrict__ num,
                                               float* __restrict__ denom) {
    __shared__ __align__(16) u16 sK[2][KVTILE * D];   // 2 x 16 KB
    __shared__ __align__(16) u16 sV[2][KVTILE * D];   // 2 x 16 KB

    const int bx = blockIdx.x;
    const int qb = bx >> 3;
    const int sp = bx & 7;           // == XCD under %8 round-robin
    const int qrow0 = qb * QBLK;
    const int kv0 = sp * KV_PER_SPLIT;

    const int tid = threadIdx.x;
    const int w = tid >> 6;
    const int lane = tid & 63;
    const int h = lane >> 5;
    const int ln5 = lane & 31;
    const int x15 = ln5 & 15;

    // --- Q B-fragments in registers (col=ln5=q, k=d) ---
    const int q = qrow0 + 32 * w + ln5;
    const float invq = invnrm[q];
    s16x8 qf[8];
#pragma unroll
    for (int ks = 0; ks < 8; ++ks) {
        const float* p = x + (size_t)q * D + 16 * ks + 8 * h;
        float4 a = *(const float4*)p;
        float4 b = *(const float4*)(p + 4);
        union { unsigned u[4]; s16x8 v; } pk;
        pk.u[0] = pk2(a.x * invq, a.y * invq);
        pk.u[1] = pk2(a.z * invq, a.w * invq);
        pk.u[2] = pk2(b.x * invq, b.y * invq);
        pk.u[3] = pk2(b.z * invq, b.w * invq);
        qf[ks] = pk.v;
    }

    f32x16 acc[4];
#pragma unroll
    for (int dt = 0; dt < 4; ++dt)
#pragma unroll
        for (int r = 0; r < 16; ++r) acc[dt][r] = 0.f;
    float rowsum = 0.f;

    // ---- prologue: stage tile 0 ----
    {
        float4 kr[4][2], vr[8];
        float kinv[4];
        stage_load(x, invnrm, kv0, tid, kr, kinv, vr);
        stage_write(tid, sK[0], sV[0], kr, kinv, vr);
    }
    __syncthreads();

    for (int tile = 0; tile < NT; ++tile) {
        const int cur = tile & 1;
        const bool pf = (tile + 1 < NT);
        const u16* bK = sK[cur];
        const u16* bV = sV[cur];

        // issue next-tile global loads early (T14: latency hides under compute)
        float4 kr[4][2], vr[8];
        float kinv[4];
        if (pf) stage_load(x, invnrm, kv0 + (tile + 1) * KVTILE, tid, kr, kinv, vr);

#pragma unroll
        for (int ct = 0; ct < 2; ++ct) {
            // ---- S^T[kv, q] = K Q^T over d=128, 2 independent MFMA chains ----
            const int kvr = 32 * ct + ln5;
            const char* krow = (const char*)bK + kvr * 256;
            f32x16 sa, sb;
#pragma unroll
            for (int r = 0; r < 16; ++r) { sa[r] = 0.f; sb[r] = 0.f; }
            __builtin_amdgcn_s_setprio(1);
#pragma unroll
            for (int ks = 0; ks < 8; ++ks) {
                s16x8 kf = *(const s16x8*)(krow + 16 * ((2 * ks + h) ^ x15));
                if (ks & 1)
                    sb = __builtin_amdgcn_mfma_f32_32x32x16_bf16(kf, qf[ks], sb, 0, 0, 0);
                else
                    sa = __builtin_amdgcn_mfma_f32_32x32x16_bf16(kf, qf[ks], sa, 0, 0, 0);
            }
            __builtin_amdgcn_s_setprio(0);

            // ---- P = exp(S), row q = ln5 in registers ----
            float p[16];
#pragma unroll
            for (int r = 0; r < 16; ++r) {
                p[r] = __expf(sa[r] + sb[r]);
                rowsum += p[r];
            }
            unsigned d0[4], d1[4], s0[4], s1[4];
#pragma unroll
            for (int m = 0; m < 4; ++m) {
                d0[m] = pk2(p[4 * m + 0], p[4 * m + 1]);
                d1[m] = pk2(p[4 * m + 2], p[4 * m + 3]);
            }
#pragma unroll
            for (int m = 0; m < 4; ++m) {
                s0[m] = (unsigned)__shfl_xor((int)d0[m], 32);
                s1[m] = (unsigned)__shfl_xor((int)d1[m], 32);
            }

            // ---- O += P V ----
#pragma unroll
            for (int kt2 = 0; kt2 < 2; ++kt2) {
                union { unsigned u[4]; s16x8 v; } A;
                A.u[0] = h ? s0[2 * kt2 + 1] : d0[2 * kt2];
                A.u[1] = h ? s1[2 * kt2 + 1] : d1[2 * kt2];
                A.u[2] = h ? d0[2 * kt2 + 1] : s0[2 * kt2];
                A.u[3] = h ? d1[2 * kt2 + 1] : s1[2 * kt2];
                const int ktg = 2 * ct + kt2;
                const int ccv = (8 * (ln5 & 1) + 2 * ktg + h + (ln5 >> 1)) & 15;
                __builtin_amdgcn_s_setprio(1);
#pragma unroll
                for (int dt = 0; dt < 4; ++dt) {
                    s16x8 vf = *(const s16x8*)((const char*)bV +
                                               (16 * dt + (ln5 >> 1)) * 256 + 16 * ccv);
                    acc[dt] = __builtin_amdgcn_mfma_f32_32x32x16_bf16(A.v, vf, acc[dt], 0, 0, 0);
                }
                __builtin_amdgcn_s_setprio(0);
            }
        }

        // convert + write next tile into the other buffer, then one barrier
        if (pf) stage_write(tid, sK[cur ^ 1], sV[cur ^ 1], kr, kinv, vr);
        __syncthreads();
    }

    // ---- epilogue: combine partials via device-scope atomics ----
    float tot = rowsum + __shfl_xor(rowsum, 32);
    if (h == 0) atomicAdd(&denom[q], tot);
#pragma unroll
    for (int dt = 0; dt < 4; ++dt)
#pragma unroll
        for (int r = 0; r < 16; ++r) {
            int qr = qrow0 + 32 * w + (r & 3) + 8 * (r >> 2) + 4 * h;
            atomicAdd(&num[(size_t)qr * D + 32 * dt + ln5], acc[dt][r]);
        }
}

// ---------------- finalize: y = 2x - num/denom ; LayerNorm ----------------
__global__ __launch_bounds__(256) void finalize(const float* __restrict__ x,
                                                const float* __restrict__ gamma,
                                                const float* __restrict__ beta,
                                                const float* __restrict__ denom,
                                                float* __restrict__ out) {  // out == num, in place
    int t = threadIdx.x;
    int row = blockIdx.x * 64 + (t >> 2);
    int q = t & 3;
    float invd = 1.0f / denom[row];
    const float4* xr = (const float4*)(x + (size_t)row * D);
    const float4* nr = (const float4*)(out + (size_t)row * D);
    float y[32];
    float s1 = 0.f, s2 = 0.f;
#pragma unroll
    for (int i = 0; i < 8; ++i) {
        float4 xv = xr[q * 8 + i];
        float4 nv = nr[q * 8 + i];
#pragma unroll
        for (int j = 0; j < 4; ++j) {
            float yv = (1.0f + SCALE) * (&xv.x)[j] - SCALE * ((&nv.x)[j] * invd);
            y[i * 4 + j] = yv;
            s1 += yv;
            s2 += yv * yv;
        }
    }
    s1 += __shfl_xor(s1, 1); s1 += __shfl_xor(s1, 2);
    s2 += __shfl_xor(s2, 1); s2 += __shfl_xor(s2, 2);
    float mu = s1 * (1.0f / D);
    float var = s2 * (1.0f / D) - mu * mu;
    float rstd = rsqrtf(var + LN_EPS);
    float4* orow = (float4*)(out + (size_t)row * D);
#pragma unroll
    for (int i = 0; i < 8; ++i) {
        int c = q * 32 + i * 4;
        float4 o;
#pragma unroll
        for (int j = 0; j < 4; ++j)
            (&o.x)[j] = (y[i * 4 + j] - mu) * rstd * gamma[c + j] + beta[c + j];
        orow[q * 8 + i] = o;
    }
}

extern "C" void kernel_launch(void* const* d_in, const int* in_sizes, int n_in,
                              void* d_out, int out_size, void* d_ws, size_t ws_size,
                              hipStream_t stream) {
    const float* x = (const float*)d_in[0];
    const float* gamma = (const float*)d_in[1];
    const float* beta = (const float*)d_in[2];
    float* out = (float*)d_out;
    float* invnrm = (float*)d_ws;             // N floats
    float* denom = invnrm + N_ROWS;           // N floats

    hipMemsetAsync(d_out, 0, (size_t)N_ROWS * D * sizeof(float), stream);  // num accumulator
    hipMemsetAsync(denom, 0, (size_t)N_ROWS * sizeof(float), stream);

    prep_norms<<<N_ROWS / 64, 256, 0, stream>>>(x, invnrm);
    attn<<<(N_ROWS / QBLK) * NSPLIT, 256, 0, stream>>>(x, invnrm, out, denom);
    finalize<<<N_ROWS / 64, 256, 0, stream>>>(x, gamma, beta, denom, out);
}